// Round 17
// baseline (36.048 us; speedup 1.0000x reference)
//
#include <hip/hip_runtime.h>
#include <math.h>

#define BLK   512
#define WIN   768         // = chunk + 2*halo
#define CHUNK 512
#define HALO  128
#define NW    (BLK/64)    // 8 waves: 0-3 heavy (2 elems/thread), 4-7 light (1)

typedef float v2f __attribute__((ext_vector_type(2)));

__device__ __forceinline__ float frcp(float x){ return __builtin_amdgcn_rcpf(x); }
__device__ __forceinline__ v2f mkv2(float x, float y){ v2f r; r.x=x; r.y=y; return r; }

// Tuples as 2x2 rows (v2f). Symmetric mats keep both rows (r1.x dups r0.y).
struct FT { v2f A0,A1,b,C0,C1,e,J0,J1; };   // filter scan tuple: 16 floats
struct ST { v2f E0,E1,g,L0,L1; };            // smoother scan tuple: 10 floats
struct BC { v2f b,C0,C1; };                  // filter prefix state (b,C only)
struct GL { v2f g,L0,L1; };                  // smoother prefix state (g,L only)

// DPP move (VALU pipe, no LDS latency). CTRL is an immediate.
template<int CTRL, typename T>
__device__ __forceinline__ T dpp_mov(const T& v){
  T r; const int* s=(const int*)&v; int* p=(int*)&r;
  constexpr int n = sizeof(T)/4;
  #pragma unroll
  for (int i=0;i<n;i++)
    p[i] = __builtin_amdgcn_update_dpp(s[i], s[i], CTRL, 0xf, 0xf, false);
  return r;
}
template<typename T>
__device__ __forceinline__ T shflup(const T& v, int d){
  T r; const float* s=(const float*)&v; float* p=(float*)&r;
  constexpr int n = sizeof(T)/4;
  #pragma unroll
  for (int i=0;i<n;i++) p[i] = __shfl_up(s[i], (unsigned)d, 64);
  return r;
}
template<typename T>
__device__ __forceinline__ T shflrev(const T& v, int revl){
  T r; const float* s=(const float*)&v; float* p=(float*)&r;
  constexpr int n = sizeof(T)/4;
  #pragma unroll
  for (int i=0;i<n;i++) p[i] = __shfl(s[i], revl, 64);
  return r;
}
// comp-major LDS exchange
template<typename T>
__device__ __forceinline__ void lds_store(float (*arr)[NW], int col, const T& v){
  const float* s=(const float*)&v;
  constexpr int n = sizeof(T)/4;
  #pragma unroll
  for (int i=0;i<n;i++) arr[i][col] = s[i];
}
template<typename T>
__device__ __forceinline__ T lds_load(const float (*arr)[NW], int col){
  T r; float* p=(float*)&r;
  constexpr int n = sizeof(T)/4;
  #pragma unroll
  for (int i=0;i<n;i++) p[i] = arr[i][col];
  return r;
}

// ---------------------------------------------------------------------------
// Full filter combine (a = earlier/smaller k, b = later).
// ---------------------------------------------------------------------------
__device__ __forceinline__ FT comb_f(const FT& a, const FT& b){
  FT o;
  v2f T0 = a.C0.x*b.J0 + a.C0.y*b.J1; T0.x += 1.f;
  v2f T1 = a.C1.x*b.J0 + a.C1.y*b.J1; T1.y += 1.f;
  const float idet = frcp(T0.x*T1.y - T0.y*T1.x);
  const v2f M0 = idet * mkv2( T1.y, -T0.y);
  const v2f M1 = idet * mkv2(-T1.x,  T0.x);
  const v2f P0 = b.A0.x*M0 + b.A0.y*M1;
  const v2f P1 = b.A1.x*M0 + b.A1.y*M1;
  o.A0 = P0.x*a.A0 + P0.y*a.A1;
  o.A1 = P1.x*a.A0 + P1.y*a.A1;
  const v2f u = a.b + b.e.x*a.C0 + b.e.y*a.C1;
  o.b = mkv2(P0.x*u.x + P0.y*u.y + b.b.x,
             P1.x*u.x + P1.y*u.y + b.b.y);
  const v2f W0 = P0.x*a.C0 + P0.y*a.C1;
  const v2f W1 = P1.x*a.C0 + P1.y*a.C1;
  const float c00 = W0.x*b.A0.x + W0.y*b.A0.y + b.C0.x;
  const float c01 = W0.x*b.A1.x + W0.y*b.A1.y + b.C0.y;
  const float c11 = W1.x*b.A1.x + W1.y*b.A1.y + b.C1.y;
  o.C0 = mkv2(c00,c01); o.C1 = mkv2(c01,c11);
  const v2f v = b.e - (a.b.x*b.J0 + a.b.y*b.J1);
  const v2f Nv = v.x*M0 + v.y*M1;
  o.e = a.e + Nv.x*a.A0 + Nv.y*a.A1;
  const v2f X0 = M0.x*b.J0 + M1.x*b.J1;
  const v2f X1 = M0.y*b.J0 + M1.y*b.J1;
  const v2f Y0 = a.A0.x*X0 + a.A1.x*X1;
  const v2f Y1 = a.A0.y*X0 + a.A1.y*X1;
  const float j00 = Y0.x*a.A0.x + Y0.y*a.A1.x + a.J0.x;
  const float j01 = Y0.x*a.A0.y + Y0.y*a.A1.y + a.J0.y;
  const float j11 = Y1.x*a.A0.y + Y1.y*a.A1.y + a.J1.y;
  o.J0 = mkv2(j00,j01); o.J1 = mkv2(j01,j11);
  return o;
}

// Prefix step: a = accumulated prefix (only b,C live), b = next segment.
// a = {0,0,0} is an exact identity (C=0 -> M=I).
__device__ __forceinline__ BC comb_bc(const BC& a, const FT& b){
  BC o;
  v2f T0 = a.C0.x*b.J0 + a.C0.y*b.J1; T0.x += 1.f;
  v2f T1 = a.C1.x*b.J0 + a.C1.y*b.J1; T1.y += 1.f;
  const float idet = frcp(T0.x*T1.y - T0.y*T1.x);
  const v2f M0 = idet * mkv2( T1.y, -T0.y);
  const v2f M1 = idet * mkv2(-T1.x,  T0.x);
  const v2f P0 = b.A0.x*M0 + b.A0.y*M1;
  const v2f P1 = b.A1.x*M0 + b.A1.y*M1;
  const v2f u = a.b + b.e.x*a.C0 + b.e.y*a.C1;
  o.b = mkv2(P0.x*u.x + P0.y*u.y + b.b.x,
             P1.x*u.x + P1.y*u.y + b.b.y);
  const v2f W0 = P0.x*a.C0 + P0.y*a.C1;
  const v2f W1 = P1.x*a.C0 + P1.y*a.C1;
  const float c00 = W0.x*b.A0.x + W0.y*b.A0.y + b.C0.x;
  const float c01 = W0.x*b.A1.x + W0.y*b.A1.y + b.C0.y;
  const float c11 = W1.x*b.A1.x + W1.y*b.A1.y + b.C1.y;
  o.C0 = mkv2(c00,c01); o.C1 = mkv2(c01,c11);
  return o;
}

// Full smoother combine (a covers LARGER k, b smaller).
__device__ __forceinline__ ST comb_s(const ST& a, const ST& b){
  ST o;
  o.E0 = b.E0.x*a.E0 + b.E0.y*a.E1;
  o.E1 = b.E1.x*a.E0 + b.E1.y*a.E1;
  o.g = mkv2(b.E0.x*a.g.x + b.E0.y*a.g.y + b.g.x,
             b.E1.x*a.g.x + b.E1.y*a.g.y + b.g.y);
  const v2f W0 = b.E0.x*a.L0 + b.E0.y*a.L1;
  const v2f W1 = b.E1.x*a.L0 + b.E1.y*a.L1;
  const float l00 = W0.x*b.E0.x + W0.y*b.E0.y + b.L0.x;
  const float l01 = W0.x*b.E1.x + W0.y*b.E1.y + b.L0.y;
  const float l11 = W1.x*b.E1.x + W1.y*b.E1.y + b.L1.y;
  o.L0 = mkv2(l00,l01); o.L1 = mkv2(l01,l11);
  return o;
}
// Prefix step: a = accumulated (g,L) covering larger k, b smaller.
// a = {0,0,0} is an exact identity.
__device__ __forceinline__ GL comb_gl(const GL& a, const ST& b){
  GL o;
  o.g = mkv2(b.E0.x*a.g.x + b.E0.y*a.g.y + b.g.x,
             b.E1.x*a.g.x + b.E1.y*a.g.y + b.g.y);
  const v2f W0 = b.E0.x*a.L0 + b.E0.y*a.L1;
  const v2f W1 = b.E1.x*a.L0 + b.E1.y*a.L1;
  const float l00 = W0.x*b.E0.x + W0.y*b.E0.y + b.L0.x;
  const float l01 = W0.x*b.E1.x + W0.y*b.E1.y + b.L0.y;
  const float l11 = W1.x*b.E1.x + W1.y*b.E1.y + b.L1.y;
  o.L0 = mkv2(l00,l01); o.L1 = mkv2(l01,l11);
  return o;
}

// f64 only here: Q = P_inf - A P_inf A^T cancels like (4/3)(lam dt)^3.
__device__ __forceinline__ void compute_fq(double dt, double lam, double s2,
    v2f& F0, v2f& F1, v2f& Q0, v2f& Q1){
  const double ld = lam*dt, e = exp(-ld), e2 = e*e;
  F0 = mkv2((float)(e*(1.0+ld)), (float)(e*dt));
  F1 = mkv2((float)(-lam*lam*dt*e), (float)(e*(1.0-ld)));
  const float q00 = (float)(s2*(1.0 - e2*((1.0+ld)*(1.0+ld)+ld*ld)));
  const float q01 = (float)(2.0*s2*lam*e2*ld*ld);
  const float q11 = (float)(lam*lam*s2*(1.0 - e2*(ld*ld+(1.0-ld)*(1.0-ld))));
  Q0 = mkv2(q00,q01); Q1 = mkv2(q01,q11);
}

__device__ __forceinline__ FT build_felem(bool prior,
    const v2f F0, const v2f F1, const v2f Q0, const v2f Q1,
    float n1, float n2, float sigma2, float lam2s2)
{
  FT e;
  const float R = frcp(n2);
  const float yy = n1*R;
  if (prior){
    e.A0 = mkv2(0.f,0.f); e.A1 = mkv2(0.f,0.f);
    const float K0 = sigma2*frcp(sigma2 + R);
    e.b = mkv2(K0*yy, 0.f);
    e.C0 = mkv2(sigma2 - K0*sigma2, 0.f); e.C1 = mkv2(0.f, lam2s2);
    e.e = mkv2(0.f,0.f); e.J0 = mkv2(0.f,0.f); e.J1 = mkv2(0.f,0.f);
  } else {
    const float iS = frcp(Q0.x + R);
    const float K0 = Q0.x*iS, K1 = Q0.y*iS;
    const float om = 1.f - K0;
    e.A0 = om*F0;
    e.A1 = F1 - K1*F0;
    e.b = mkv2(K0*yy, K1*yy);
    e.C0 = om*Q0;
    e.C1 = mkv2(e.C0.y, Q1.y - K1*Q0.y);
    e.e = (yy*iS)*F0;
    e.J0 = (iS*F0.x)*F0;
    e.J1 = mkv2(e.J0.y, iS*F0.y*F0.y);
  }
  return e;
}

__device__ __forceinline__ ST build_selem(const v2f m, const v2f Pf0, const v2f Pf1,
    const v2f F0, const v2f F1, const v2f Q0, const v2f Q1)
{
  ST e;
  const v2f W0 = F0.x*Pf0 + F0.y*Pf1;        // W = F Pf (Pf sym)
  const v2f W1 = F1.x*Pf0 + F1.y*Pf1;
  const float Pp00 = W0.x*F0.x + W0.y*F0.y + Q0.x;
  const float Pp01 = W0.x*F1.x + W0.y*F1.y + Q0.y;
  const float Pp11 = W1.x*F1.x + W1.y*F1.y + Q1.y;
  const float idet = frcp(Pp00*Pp11 - Pp01*Pp01);
  const v2f Pi0 = idet * mkv2( Pp11, -Pp01);
  const v2f Pi1 = idet * mkv2(-Pp01,  Pp00);
  e.E0 = W0.x*Pi0 + W1.x*Pi1;                // E = (Pf F^T) Pp^-1 = W^T Pp^-1
  e.E1 = W0.y*Pi0 + W1.y*Pi1;
  const float mp0 = F0.x*m.x + F0.y*m.y;
  const float mp1 = F1.x*m.x + F1.y*m.y;
  e.g = mkv2(m.x - (e.E0.x*mp0 + e.E0.y*mp1),
             m.y - (e.E1.x*mp0 + e.E1.y*mp1));
  const v2f Ppr0 = mkv2(Pp00,Pp01), Ppr1 = mkv2(Pp01,Pp11);
  const v2f Z0 = e.E0.x*Ppr0 + e.E0.y*Ppr1;
  const v2f Z1 = e.E1.x*Ppr0 + e.E1.y*Ppr1;
  const float l00 = Pf0.x - (Z0.x*e.E0.x + Z0.y*e.E0.y);
  const float l01 = Pf0.y - (Z0.x*e.E1.x + Z0.y*e.E1.y);
  const float l11 = Pf1.y - (Z1.x*e.E1.x + Z1.y*e.E1.y);
  e.L0 = mkv2(l00,l01); e.L1 = mkv2(l01,l11);
  return e;
}

// ---------------------------------------------------------------------------
// Fixed-lag windowed EP (WIN=768, HALO=128) with HETEROGENEOUS EPT:
// threads 0..255 (waves 0-3) own 2 window elems each (0..511); threads
// 256..511 (waves 4-7) own 1 elem each (512..767). Scan stays lane-monotone;
// every SIMD carries one heavy + one light wave -> balanced issue + stall
// filling. DPP scans; 2 barriers/iter; BC/GL wave chains.
// ---------------------------------------------------------------------------
__global__ __launch_bounds__(BLK, 1) void fused_kernel(
    const float* __restrict__ times, const int* __restrict__ y,
    const float* __restrict__ ll, const float* __restrict__ lv,
    float* __restrict__ out, int N)
{
  __shared__ float shF[16][NW];   // filter wave aggregates (full FT)
  __shared__ float shS[10][NW];   // smoother wave aggregates (full ST)

  const int t = threadIdx.x, b = blockIdx.x;
  const int lane = t & 63, w = t >> 6;
  const int revl = 63 - lane;
  const bool heavy = (t < 256);
  const int cs = b * CHUNK;
  int ws = cs - HALO;
  if (ws < 0) ws = 0;
  if (ws > N - WIN) ws = N - WIN;
  const int g0 = heavy ? (ws + 2*t) : (ws + 256 + t);

  const double lamd    = sqrt(3.0)/exp((double)ll[0]);
  const double sigma2d = exp((double)lv[0]);
  const float sigma2 = (float)sigma2d;
  const float lam2s2 = (float)(lamd*lamd*sigma2d);

  // F/Q rows, iteration-invariant.
  // heavy: [0]=step into elem0, [1]=into elem1, [2]=into next thread's elem0.
  // light: [0]=step into its elem, [1]=into next elem. [2] unused.
  v2f aF0[3], aF1[3], aQ0[3], aQ1[3];
  {
    const float tm1 = (g0 > 0) ? times[g0-1] : 0.f;
    const float t0 = times[g0];
    const float t1 = (g0+1 <= N-1) ? times[g0+1] : t0;
    compute_fq((g0==0) ? 0.0 : ((double)t0-(double)tm1), lamd, sigma2d,
               aF0[0],aF1[0],aQ0[0],aQ1[0]);
    compute_fq((double)t1-(double)t0, lamd, sigma2d,
               aF0[1],aF1[1],aQ0[1],aQ1[1]);
    if (heavy){
      const float t2 = times[g0+2];   // ws+2t+2 <= ws+512 < N always
      compute_fq((double)t2-(double)t1, lamd, sigma2d,
                 aF0[2],aF1[2],aQ0[2],aQ1[2]);
    }
  }
  float yf[2];
  yf[0] = (float)y[g0];
  yf[1] = heavy ? (float)y[g0+1] : 0.f;

  float nat1[2], nat2[2], qm[2], qv[2];
  #pragma unroll
  for (int c=0;c<2;c++){ nat1[c]=0.f; nat2[c]=1e-6f; qm[c]=0.f; qv[c]=1.f; }

  const bool priorElem = (t == 0);
  const bool lastThr   = (t == BLK-1);   // light wave, window elem WIN-1

  for (int it=0; it<4; ++it){
    // ---- site update (analytic Poisson moment E[e^f]=exp(cm+cv/2)) ----
    const int nc = heavy ? 2 : 1;
    for (int c=0;c<nc;c++){
      const float iqv = frcp(qv[c]);
      const float cp = fmaxf(iqv - nat2[c], 1e-6f);
      const float cv = frcp(cp);
      const float cm = cv*(qm[c]*iqv - nat1[c]);
      const float Ee = __expf(cm + 0.5f*cv);
      const float np  = fmaxf(Ee, 1e-6f);
      const float nn1 = (yf[c] - Ee) + np*cm;
      nat1[c] = 0.5f*nat1[c] + 0.5f*nn1;
      nat2[c] = fmaxf(0.5f*nat2[c] + 0.5f*np, 1e-6f);
    }

    // ================= FILTER =================
    FT part0 = build_felem(priorElem, aF0[0],aF1[0],aQ0[0],aQ1[0],
                           nat1[0], nat2[0], sigma2, lam2s2);
    FT part1;
    if (heavy){
      const FT e1 = build_felem(false, aF0[1],aF1[1],aQ0[1],aQ1[1],
                                nat1[1], nat2[1], sigma2, lam2s2);
      part1 = comb_f(part0, e1);
    } else {
      part1 = part0;
    }
    FT acc = part1;
    // DPP wave inclusive scan (ascending)
    { const FT p = dpp_mov<0x111>(acc); if ((lane&15)>=1) acc = comb_f(p, acc); }
    { const FT p = dpp_mov<0x112>(acc); if ((lane&15)>=2) acc = comb_f(p, acc); }
    { const FT p = dpp_mov<0x114>(acc); if ((lane&15)>=4) acc = comb_f(p, acc); }
    { const FT p = dpp_mov<0x118>(acc); if ((lane&15)>=8) acc = comb_f(p, acc); }
    { const FT p = dpp_mov<0x142>(acc); if (lane & 16)    acc = comb_f(p, acc); }
    { const FT p = dpp_mov<0x143>(acc); if (lane >= 32)   acc = comb_f(p, acc); }
    if (lane == 63) lds_store(shF, w, acc);
    __syncthreads();
    // block prefix as BC chain over earlier waves (identity = zeros)
    BC pre; pre.b=mkv2(0.f,0.f); pre.C0=mkv2(0.f,0.f); pre.C1=mkv2(0.f,0.f);
    for (int j=0; j<w; ++j){
      const FT a = lds_load<FT>(shF, j);
      pre = comb_bc(pre, a);
    }
    {
      const FT lex = shflup(acc, 1);
      if (lane > 0) pre = comb_bc(pre, lex);
    }
    // apply stored partials
    v2f mv[2], Pr0[2], Pr1[2];
    {
      const BC r0 = comb_bc(pre, part0);
      mv[0]=r0.b; Pr0[0]=r0.C0; Pr1[0]=r0.C1;
      if (heavy){
        const BC r1 = comb_bc(pre, part1);
        mv[1]=r1.b; Pr0[1]=r1.C0; Pr1[1]=r1.C1;
      }
    }

    // ================= SMOOTHER (descending k, lane-reversed domain) ========
    const int rw = NW-1-w;
    ST spart0, spart1;
    if (heavy){
      spart1 = build_selem(mv[1], Pr0[1], Pr1[1], aF0[2],aF1[2],aQ0[2],aQ1[2]);
      const ST e0 = build_selem(mv[0], Pr0[0], Pr1[0], aF0[1],aF1[1],aQ0[1],aQ1[1]);
      spart0 = comb_s(spart1, e0);
    } else {
      if (lastThr){
        spart0.E0 = mkv2(0.f,0.f); spart0.E1 = mkv2(0.f,0.f);
        spart0.g = mv[0]; spart0.L0 = Pr0[0]; spart0.L1 = Pr1[0];
      } else {
        spart0 = build_selem(mv[0], Pr0[0], Pr1[0], aF0[1],aF1[1],aQ0[1],aQ1[1]);
      }
      spart1 = spart0;
    }
    // flip to reversed lanes (phys lane l holds original lane 63-l)
    const ST sflip0 = shflrev(spart0, revl);
    ST sacc = sflip0;
    // ascending DPP scan in flipped domain (lower phys lane = larger k = 'a')
    { const ST p = dpp_mov<0x111>(sacc); if ((lane&15)>=1) sacc = comb_s(p, sacc); }
    { const ST p = dpp_mov<0x112>(sacc); if ((lane&15)>=2) sacc = comb_s(p, sacc); }
    { const ST p = dpp_mov<0x114>(sacc); if ((lane&15)>=4) sacc = comb_s(p, sacc); }
    { const ST p = dpp_mov<0x118>(sacc); if ((lane&15)>=8) sacc = comb_s(p, sacc); }
    { const ST p = dpp_mov<0x142>(sacc); if (lane & 16)    sacc = comb_s(p, sacc); }
    { const ST p = dpp_mov<0x143>(sacc); if (lane >= 32)   sacc = comb_s(p, sacc); }
    if (lane == 63) lds_store(shS, rw, sacc);
    __syncthreads();
    // block prefix as GL chain over earlier (larger-k) waves
    GL spre; spre.g=mkv2(0.f,0.f); spre.L0=mkv2(0.f,0.f); spre.L1=mkv2(0.f,0.f);
    for (int j=0; j<rw; ++j){
      const ST a = lds_load<ST>(shS, j);
      spre = comb_gl(spre, a);
    }
    {
      const ST slex = shflup(sacc, 1);
      if (lane > 0) spre = comb_gl(spre, slex);
    }
    // apply flipped partials; flip results back to original lanes
    {
      const GL r0 = comb_gl(spre, sflip0);
      qm[0] = __shfl(r0.g.x, revl, 64);
      qv[0] = fmaxf(__shfl(r0.L0.x, revl, 64), 1e-12f);
      if (heavy){
        const ST sflip1 = shflrev(spart1, revl);
        const GL r1 = comb_gl(spre, sflip1);
        qm[1] = __shfl(r1.g.x, revl, 64);
        qv[1] = fmaxf(__shfl(r1.L0.x, revl, 64), 1e-12f);
      }
    }

    if (it == 3){
      if (g0 >= cs && g0 < cs + CHUNK) out[g0] = qm[0];
      if (heavy && (g0+1 >= cs && g0+1 < cs + CHUNK)) out[g0+1] = qm[1];
    }
  }
}

// ---------------------------------------------------------------------------
extern "C" void kernel_launch(void* const* d_in, const int* in_sizes, int n_in,
                              void* d_out, int out_size, void* d_ws, size_t ws_size,
                              hipStream_t stream) {
  (void)n_in; (void)out_size; (void)d_ws; (void)ws_size;
  const int N = in_sizes[0];                 // 131072
  const float* times = (const float*)d_in[0];
  const int*   y     = (const int*)d_in[1];
  const float* ll    = (const float*)d_in[2];
  const float* lv    = (const float*)d_in[3];
  float* out = (float*)d_out;

  const int G = N / CHUNK;                   // 256 blocks, one per CU
  fused_kernel<<<G, BLK, 0, stream>>>(times, y, ll, lv, out, N);
}

// Round 18
// 27.667 us; speedup vs baseline: 1.3029x; 1.3029x over previous
//
#include <hip/hip_runtime.h>
#include <math.h>

#define BLK   256
#define EPT   3
#define WIN   (BLK*EPT)   // 768 = chunk + 2*halo
#define CHUNK 512
#define HALO  128
#define NW    (BLK/64)    // 4 waves, exactly 1 per SIMD

typedef float v2f __attribute__((ext_vector_type(2)));

__device__ __forceinline__ float frcp(float x){ return __builtin_amdgcn_rcpf(x); }
__device__ __forceinline__ v2f mkv2(float x, float y){ v2f r; r.x=x; r.y=y; return r; }

// Tuples as 2x2 rows (v2f). Symmetric mats keep both rows (r1.x dups r0.y).
struct FT { v2f A0,A1,b,C0,C1,e,J0,J1; };   // filter scan tuple: 16 floats
struct ST { v2f E0,E1,g,L0,L1; };            // smoother scan tuple: 10 floats
struct BC { v2f b,C0,C1; };                  // filter prefix state (b,C only)
struct GL { v2f g,L0,L1; };                  // smoother prefix state (g,L only)

template<typename T>
__device__ __forceinline__ T shflup(const T& v, int d){
  T r; const float* s=(const float*)&v; float* p=(float*)&r;
  constexpr int n = sizeof(T)/4;
  #pragma unroll
  for (int i=0;i<n;i++) p[i] = __shfl_up(s[i], (unsigned)d, 64);
  return r;
}
template<typename T>
__device__ __forceinline__ T shfldn(const T& v, int d){
  T r; const float* s=(const float*)&v; float* p=(float*)&r;
  constexpr int n = sizeof(T)/4;
  #pragma unroll
  for (int i=0;i<n;i++) p[i] = __shfl_down(s[i], (unsigned)d, 64);
  return r;
}
// comp-major LDS exchange
template<typename T>
__device__ __forceinline__ void lds_store(float (*arr)[NW], int col, const T& v){
  const float* s=(const float*)&v;
  constexpr int n = sizeof(T)/4;
  #pragma unroll
  for (int i=0;i<n;i++) arr[i][col] = s[i];
}
template<typename T>
__device__ __forceinline__ T lds_load(const float (*arr)[NW], int col){
  T r; float* p=(float*)&r;
  constexpr int n = sizeof(T)/4;
  #pragma unroll
  for (int i=0;i<n;i++) p[i] = arr[i][col];
  return r;
}

// ---------------------------------------------------------------------------
// Full filter combine (a = earlier/smaller k, b = later).
// ---------------------------------------------------------------------------
__device__ __forceinline__ FT comb_f(const FT& a, const FT& b){
  FT o;
  v2f T0 = a.C0.x*b.J0 + a.C0.y*b.J1; T0.x += 1.f;
  v2f T1 = a.C1.x*b.J0 + a.C1.y*b.J1; T1.y += 1.f;
  const float idet = frcp(T0.x*T1.y - T0.y*T1.x);
  const v2f M0 = idet * mkv2( T1.y, -T0.y);
  const v2f M1 = idet * mkv2(-T1.x,  T0.x);
  const v2f P0 = b.A0.x*M0 + b.A0.y*M1;
  const v2f P1 = b.A1.x*M0 + b.A1.y*M1;
  o.A0 = P0.x*a.A0 + P0.y*a.A1;
  o.A1 = P1.x*a.A0 + P1.y*a.A1;
  const v2f u = a.b + b.e.x*a.C0 + b.e.y*a.C1;
  o.b = mkv2(P0.x*u.x + P0.y*u.y + b.b.x,
             P1.x*u.x + P1.y*u.y + b.b.y);
  const v2f W0 = P0.x*a.C0 + P0.y*a.C1;
  const v2f W1 = P1.x*a.C0 + P1.y*a.C1;
  const float c00 = W0.x*b.A0.x + W0.y*b.A0.y + b.C0.x;
  const float c01 = W0.x*b.A1.x + W0.y*b.A1.y + b.C0.y;
  const float c11 = W1.x*b.A1.x + W1.y*b.A1.y + b.C1.y;
  o.C0 = mkv2(c00,c01); o.C1 = mkv2(c01,c11);
  const v2f v = b.e - (a.b.x*b.J0 + a.b.y*b.J1);
  const v2f Nv = v.x*M0 + v.y*M1;
  o.e = a.e + Nv.x*a.A0 + Nv.y*a.A1;
  const v2f X0 = M0.x*b.J0 + M1.x*b.J1;
  const v2f X1 = M0.y*b.J0 + M1.y*b.J1;
  const v2f Y0 = a.A0.x*X0 + a.A1.x*X1;
  const v2f Y1 = a.A0.y*X0 + a.A1.y*X1;
  const float j00 = Y0.x*a.A0.x + Y0.y*a.A1.x + a.J0.x;
  const float j01 = Y0.x*a.A0.y + Y0.y*a.A1.y + a.J0.y;
  const float j11 = Y1.x*a.A0.y + Y1.y*a.A1.y + a.J1.y;
  o.J0 = mkv2(j00,j01); o.J1 = mkv2(j01,j11);
  return o;
}

// Prefix step: a = accumulated prefix (only b,C live), b = next segment.
// a = {0,0,0} is an exact identity (C=0 -> M=I).
__device__ __forceinline__ BC comb_bc(const BC& a, const FT& b){
  BC o;
  v2f T0 = a.C0.x*b.J0 + a.C0.y*b.J1; T0.x += 1.f;
  v2f T1 = a.C1.x*b.J0 + a.C1.y*b.J1; T1.y += 1.f;
  const float idet = frcp(T0.x*T1.y - T0.y*T1.x);
  const v2f M0 = idet * mkv2( T1.y, -T0.y);
  const v2f M1 = idet * mkv2(-T1.x,  T0.x);
  const v2f P0 = b.A0.x*M0 + b.A0.y*M1;
  const v2f P1 = b.A1.x*M0 + b.A1.y*M1;
  const v2f u = a.b + b.e.x*a.C0 + b.e.y*a.C1;
  o.b = mkv2(P0.x*u.x + P0.y*u.y + b.b.x,
             P1.x*u.x + P1.y*u.y + b.b.y);
  const v2f W0 = P0.x*a.C0 + P0.y*a.C1;
  const v2f W1 = P1.x*a.C0 + P1.y*a.C1;
  const float c00 = W0.x*b.A0.x + W0.y*b.A0.y + b.C0.x;
  const float c01 = W0.x*b.A1.x + W0.y*b.A1.y + b.C0.y;
  const float c11 = W1.x*b.A1.x + W1.y*b.A1.y + b.C1.y;
  o.C0 = mkv2(c00,c01); o.C1 = mkv2(c01,c11);
  return o;
}

// Full smoother combine (a covers LARGER k, b smaller).
__device__ __forceinline__ ST comb_s(const ST& a, const ST& b){
  ST o;
  o.E0 = b.E0.x*a.E0 + b.E0.y*a.E1;
  o.E1 = b.E1.x*a.E0 + b.E1.y*a.E1;
  o.g = mkv2(b.E0.x*a.g.x + b.E0.y*a.g.y + b.g.x,
             b.E1.x*a.g.x + b.E1.y*a.g.y + b.g.y);
  const v2f W0 = b.E0.x*a.L0 + b.E0.y*a.L1;
  const v2f W1 = b.E1.x*a.L0 + b.E1.y*a.L1;
  const float l00 = W0.x*b.E0.x + W0.y*b.E0.y + b.L0.x;
  const float l01 = W0.x*b.E1.x + W0.y*b.E1.y + b.L0.y;
  const float l11 = W1.x*b.E1.x + W1.y*b.E1.y + b.L1.y;
  o.L0 = mkv2(l00,l01); o.L1 = mkv2(l01,l11);
  return o;
}
// Prefix step: a = accumulated (g,L) covering larger k, b smaller.
// a = {0,0,0} is an exact identity.
__device__ __forceinline__ GL comb_gl(const GL& a, const ST& b){
  GL o;
  o.g = mkv2(b.E0.x*a.g.x + b.E0.y*a.g.y + b.g.x,
             b.E1.x*a.g.x + b.E1.y*a.g.y + b.g.y);
  const v2f W0 = b.E0.x*a.L0 + b.E0.y*a.L1;
  const v2f W1 = b.E1.x*a.L0 + b.E1.y*a.L1;
  const float l00 = W0.x*b.E0.x + W0.y*b.E0.y + b.L0.x;
  const float l01 = W0.x*b.E1.x + W0.y*b.E1.y + b.L0.y;
  const float l11 = W1.x*b.E1.x + W1.y*b.E1.y + b.L1.y;
  o.L0 = mkv2(l00,l01); o.L1 = mkv2(l01,l11);
  return o;
}

// f64 only here: Q = P_inf - A P_inf A^T cancels like (4/3)(lam dt)^3.
__device__ __forceinline__ void compute_fq(double dt, double lam, double s2,
    v2f& F0, v2f& F1, v2f& Q0, v2f& Q1){
  const double ld = lam*dt, e = exp(-ld), e2 = e*e;
  F0 = mkv2((float)(e*(1.0+ld)), (float)(e*dt));
  F1 = mkv2((float)(-lam*lam*dt*e), (float)(e*(1.0-ld)));
  const float q00 = (float)(s2*(1.0 - e2*((1.0+ld)*(1.0+ld)+ld*ld)));
  const float q01 = (float)(2.0*s2*lam*e2*ld*ld);
  const float q11 = (float)(lam*lam*s2*(1.0 - e2*(ld*ld+(1.0-ld)*(1.0-ld))));
  Q0 = mkv2(q00,q01); Q1 = mkv2(q01,q11);
}

__device__ __forceinline__ FT build_felem(bool prior,
    const v2f F0, const v2f F1, const v2f Q0, const v2f Q1,
    float n1, float n2, float sigma2, float lam2s2)
{
  FT e;
  const float R = frcp(n2);
  const float yy = n1*R;
  if (prior){
    e.A0 = mkv2(0.f,0.f); e.A1 = mkv2(0.f,0.f);
    const float K0 = sigma2*frcp(sigma2 + R);
    e.b = mkv2(K0*yy, 0.f);
    e.C0 = mkv2(sigma2 - K0*sigma2, 0.f); e.C1 = mkv2(0.f, lam2s2);
    e.e = mkv2(0.f,0.f); e.J0 = mkv2(0.f,0.f); e.J1 = mkv2(0.f,0.f);
  } else {
    const float iS = frcp(Q0.x + R);
    const float K0 = Q0.x*iS, K1 = Q0.y*iS;
    const float om = 1.f - K0;
    e.A0 = om*F0;
    e.A1 = F1 - K1*F0;
    e.b = mkv2(K0*yy, K1*yy);
    e.C0 = om*Q0;
    e.C1 = mkv2(e.C0.y, Q1.y - K1*Q0.y);
    e.e = (yy*iS)*F0;
    e.J0 = (iS*F0.x)*F0;
    e.J1 = mkv2(e.J0.y, iS*F0.y*F0.y);
  }
  return e;
}

__device__ __forceinline__ ST build_selem(const v2f m, const v2f Pf0, const v2f Pf1,
    const v2f F0, const v2f F1, const v2f Q0, const v2f Q1)
{
  ST e;
  const v2f W0 = F0.x*Pf0 + F0.y*Pf1;        // W = F Pf (Pf sym)
  const v2f W1 = F1.x*Pf0 + F1.y*Pf1;
  const float Pp00 = W0.x*F0.x + W0.y*F0.y + Q0.x;
  const float Pp01 = W0.x*F1.x + W0.y*F1.y + Q0.y;
  const float Pp11 = W1.x*F1.x + W1.y*F1.y + Q1.y;
  const float idet = frcp(Pp00*Pp11 - Pp01*Pp01);
  const v2f Pi0 = idet * mkv2( Pp11, -Pp01);
  const v2f Pi1 = idet * mkv2(-Pp01,  Pp00);
  e.E0 = W0.x*Pi0 + W1.x*Pi1;                // E = (Pf F^T) Pp^-1 = W^T Pp^-1
  e.E1 = W0.y*Pi0 + W1.y*Pi1;
  const float mp0 = F0.x*m.x + F0.y*m.y;
  const float mp1 = F1.x*m.x + F1.y*m.y;
  e.g = mkv2(m.x - (e.E0.x*mp0 + e.E0.y*mp1),
             m.y - (e.E1.x*mp0 + e.E1.y*mp1));
  const v2f Ppr0 = mkv2(Pp00,Pp01), Ppr1 = mkv2(Pp01,Pp11);
  const v2f Z0 = e.E0.x*Ppr0 + e.E0.y*Ppr1;
  const v2f Z1 = e.E1.x*Ppr0 + e.E1.y*Ppr1;
  const float l00 = Pf0.x - (Z0.x*e.E0.x + Z0.y*e.E0.y);
  const float l01 = Pf0.y - (Z0.x*e.E1.x + Z0.y*e.E1.y);
  const float l11 = Pf1.y - (Z1.x*e.E1.x + Z1.y*e.E1.y);
  e.L0 = mkv2(l00,l01); e.L1 = mkv2(l01,l11);
  return e;
}

// ---------------------------------------------------------------------------
// Fixed-lag windowed EP, EPT=3 / BLK=256: 4 waves, exactly 1 per SIMD
// (balanced); fixed per-thread scan cost amortized over 3 elements
// (per-element inst ~840 vs 1063 at EPT=2). Stored partials, zero-identity
// prefixes, 2 barriers/iter, BC/GL wave chains (<=3 steps).
// ---------------------------------------------------------------------------
__global__ __launch_bounds__(BLK, 1) void fused_kernel(
    const float* __restrict__ times, const int* __restrict__ y,
    const float* __restrict__ ll, const float* __restrict__ lv,
    float* __restrict__ out, int N)
{
  __shared__ float shF[16][NW];   // filter wave aggregates (full FT)
  __shared__ float shS[10][NW];   // smoother wave aggregates (full ST)

  const int t = threadIdx.x, b = blockIdx.x;
  const int lane = t & 63, w = t >> 6;
  const int cs = b * CHUNK;
  int ws = cs - HALO;
  if (ws < 0) ws = 0;
  if (ws > N - WIN) ws = N - WIN;
  const int g0 = ws + t * EPT;

  const double lamd    = sqrt(3.0)/exp((double)ll[0]);
  const double sigma2d = exp((double)lv[0]);
  const float sigma2 = (float)sigma2d;
  const float lam2s2 = (float)(lamd*lamd*sigma2d);

  // F/Q rows, iteration-invariant. [j] = step INTO local elem j (j=0..2);
  // [3] = step into next thread's first elem (smoother boundary).
  v2f aF0[EPT+1], aF1[EPT+1], aQ0[EPT+1], aQ1[EPT+1];
  {
    const float tm1 = (g0 > 0) ? times[g0-1] : 0.f;
    const float t0 = times[g0];
    const float t1 = times[g0+1];
    const float t2 = times[g0+2];
    const float t3 = (g0+3 <= N-1) ? times[g0+3] : times[N-1];
    compute_fq((g0==0) ? 0.0 : ((double)t0-(double)tm1), lamd, sigma2d, aF0[0],aF1[0],aQ0[0],aQ1[0]);
    compute_fq((double)t1-(double)t0, lamd, sigma2d, aF0[1],aF1[1],aQ0[1],aQ1[1]);
    compute_fq((double)t2-(double)t1, lamd, sigma2d, aF0[2],aF1[2],aQ0[2],aQ1[2]);
    compute_fq((double)t3-(double)t2, lamd, sigma2d, aF0[3],aF1[3],aQ0[3],aQ1[3]);
  }
  float yf[EPT];
  yf[0] = (float)y[g0]; yf[1] = (float)y[g0+1]; yf[2] = (float)y[g0+2];

  float nat1[EPT], nat2[EPT], qm[EPT], qv[EPT];
  #pragma unroll
  for (int c=0;c<EPT;c++){ nat1[c]=0.f; nat2[c]=1e-6f; qm[c]=0.f; qv[c]=1.f; }

  const bool priorElem = (t == 0);
  const bool lastThr   = (t == BLK-1);

  for (int it=0; it<4; ++it){
    // ---- site update (analytic Poisson moment E[e^f]=exp(cm+cv/2)) ----
    #pragma unroll
    for (int c=0;c<EPT;c++){
      const float iqv = frcp(qv[c]);
      const float cp = fmaxf(iqv - nat2[c], 1e-6f);
      const float cv = frcp(cp);
      const float cm = cv*(qm[c]*iqv - nat1[c]);
      const float Ee = __expf(cm + 0.5f*cv);
      const float np  = fmaxf(Ee, 1e-6f);
      const float nn1 = (yf[c] - Ee) + np*cm;
      nat1[c] = 0.5f*nat1[c] + 0.5f*nn1;
      nat2[c] = fmaxf(0.5f*nat2[c] + 0.5f*np, 1e-6f);
    }

    // ================= FILTER =================
    FT part0 = build_felem(priorElem, aF0[0],aF1[0],aQ0[0],aQ1[0],
                           nat1[0], nat2[0], sigma2, lam2s2);
    FT part1, part2;
    {
      const FT e1 = build_felem(false, aF0[1],aF1[1],aQ0[1],aQ1[1],
                                nat1[1], nat2[1], sigma2, lam2s2);
      part1 = comb_f(part0, e1);
      const FT e2 = build_felem(false, aF0[2],aF1[2],aQ0[2],aQ1[2],
                                nat1[2], nat2[2], sigma2, lam2s2);
      part2 = comb_f(part1, e2);
    }
    FT acc = part2;
    // wave inclusive scan
    #pragma unroll
    for (int d=1; d<64; d<<=1){
      const FT pre_ = shflup(acc, d);
      if (lane >= d) acc = comb_f(pre_, acc);
    }
    if (lane == 63) lds_store(shF, w, acc);
    __syncthreads();
    // block prefix as BC chain over earlier waves (identity = zeros)
    BC pre; pre.b=mkv2(0.f,0.f); pre.C0=mkv2(0.f,0.f); pre.C1=mkv2(0.f,0.f);
    for (int j=0; j<w; ++j){
      const FT a = lds_load<FT>(shF, j);
      pre = comb_bc(pre, a);
    }
    {
      const FT lex = shflup(acc, 1);
      if (lane > 0) pre = comb_bc(pre, lex);
    }
    // apply stored partials (independent -> ILP)
    v2f mv[EPT], Pr0[EPT], Pr1[EPT];
    {
      const BC r0 = comb_bc(pre, part0);
      const BC r1 = comb_bc(pre, part1);
      const BC r2 = comb_bc(pre, part2);
      mv[0]=r0.b; Pr0[0]=r0.C0; Pr1[0]=r0.C1;
      mv[1]=r1.b; Pr0[1]=r1.C0; Pr1[1]=r1.C1;
      mv[2]=r2.b; Pr0[2]=r2.C0; Pr1[2]=r2.C1;
    }

    // ================= SMOOTHER (reversed) =================
    const int rw = NW-1-w;
    ST spart2;
    if (lastThr){
      spart2.E0 = mkv2(0.f,0.f); spart2.E1 = mkv2(0.f,0.f);
      spart2.g = mv[2]; spart2.L0 = Pr0[2]; spart2.L1 = Pr1[2];
    } else {
      spart2 = build_selem(mv[2], Pr0[2], Pr1[2], aF0[3],aF1[3],aQ0[3],aQ1[3]);
    }
    ST spart1, spart0;
    {
      const ST e1 = build_selem(mv[1], Pr0[1], Pr1[1], aF0[2],aF1[2],aQ0[2],aQ1[2]);
      spart1 = comb_s(spart2, e1);
      const ST e0 = build_selem(mv[0], Pr0[0], Pr1[0], aF0[1],aF1[1],aQ0[1],aQ1[1]);
      spart0 = comb_s(spart1, e0);
    }
    ST sacc = spart0;
    // wave scan (earlier = higher lane)
    #pragma unroll
    for (int d=1; d<64; d<<=1){
      const ST pres = shfldn(sacc, d);
      if (lane + d < 64) sacc = comb_s(pres, sacc);
    }
    if (lane == 0) lds_store(shS, rw, sacc);
    __syncthreads();
    // block prefix as GL chain over earlier (larger-k) waves
    GL spre; spre.g=mkv2(0.f,0.f); spre.L0=mkv2(0.f,0.f); spre.L1=mkv2(0.f,0.f);
    for (int j=0; j<rw; ++j){
      const ST a = lds_load<ST>(shS, j);
      spre = comb_gl(spre, a);
    }
    {
      const ST slex = shfldn(sacc, 1);
      if (lane < 63) spre = comb_gl(spre, slex);
    }
    // apply stored partials
    {
      const GL r0 = comb_gl(spre, spart0);
      const GL r1 = comb_gl(spre, spart1);
      const GL r2 = comb_gl(spre, spart2);
      qm[0] = r0.g.x; qv[0] = fmaxf(r0.L0.x, 1e-12f);
      qm[1] = r1.g.x; qv[1] = fmaxf(r1.L0.x, 1e-12f);
      qm[2] = r2.g.x; qv[2] = fmaxf(r2.L0.x, 1e-12f);
    }

    if (it == 3){
      #pragma unroll
      for (int c=0;c<EPT;c++){
        const int g = g0 + c;
        if (g >= cs && g < cs + CHUNK) out[g] = qm[c];
      }
    }
  }
}

// ---------------------------------------------------------------------------
extern "C" void kernel_launch(void* const* d_in, const int* in_sizes, int n_in,
                              void* d_out, int out_size, void* d_ws, size_t ws_size,
                              hipStream_t stream) {
  (void)n_in; (void)out_size; (void)d_ws; (void)ws_size;
  const int N = in_sizes[0];                 // 131072
  const float* times = (const float*)d_in[0];
  const int*   y     = (const int*)d_in[1];
  const float* ll    = (const float*)d_in[2];
  const float* lv    = (const float*)d_in[3];
  float* out = (float*)d_out;

  const int G = N / CHUNK;                   // 256 blocks, one per CU
  fused_kernel<<<G, BLK, 0, stream>>>(times, y, ll, lv, out, N);
}